// Round 20
// baseline (148.548 us; speedup 1.0000x reference)
//
#include <hip/hip_runtime.h>
#include <hip/hip_bf16.h>

typedef __hip_bfloat16 bf16;
typedef __attribute__((ext_vector_type(8))) __bf16 bf8v;   // MFMA A/B frag (4 VGPR)
typedef __attribute__((ext_vector_type(4))) float  f4v;    // MFMA C/D frag

#define NN 512          // nodes
#define SSEQ 64         // seq len
#define DDIM 128        // model dim
#define HH 4            // heads
#define NROWS (NN*SSEQ) // 32768
#define EMAX 4096       // edge capacity (problem-fixed E)
#define ECH 64          // edges per rank-chunk

__device__ __forceinline__ float b2f(bf16 x){ return __bfloat162float(x); }
__device__ __forceinline__ bf16 f2b(float x){ return __float2bfloat16(x); }
__device__ __forceinline__ float ldf(float x){ return x; }
__device__ __forceinline__ float ldf(bf16 x){ return b2f(x); }

__device__ __forceinline__ f4v mfma16(bf8v a, bf8v b, f4v c){
  return __builtin_amdgcn_mfma_f32_16x16x32_bf16(a, b, c, 0, 0, 0);
}
__device__ __forceinline__ bf8v ldfrag(const void* p){
  return __builtin_bit_cast(bf8v, *(const int4*)p);
}
__device__ __forceinline__ float gelu_f(float v){
  return 0.5f*v*(1.0f + tanhf(0.7978845608028654f*(v + 0.044715f*v*v*v)));
}

// ---- merged prep + CSR offsets/perm + per-chunk histograms (all independent) ----
__global__ __launch_bounds__(512) void prep_all_k(
    const float* wq, const float* wk, const float* wv, const float* wo,
    const float* w1, const float* w2, const float* wsa,
    const float* w_sq, const float* b_sq,
    const float* bq, const float* bk, const float* bv,
    const int* __restrict__ receivers,
    bf16* wqkvT, bf16* woT, bf16* w1T, bf16* w2T, bf16* wsaTt,
    bf16* wbarT, float* bbar, float* qkv_bias,
    int* off, int* perm, int* chunk_cnt, int E){
  int b = blockIdx.x, t = threadIdx.x;
  if (b < 832){
    if (t >= 256) return;
    const float* W; bf16* Wt; int K, lN, rel, roff = 0;
    if      (b < 64) { W=wq;  Wt=wqkvT; K=128; lN=7; rel=b;     roff=0;   }
    else if (b <128) { W=wk;  Wt=wqkvT; K=128; lN=7; rel=b-64;  roff=128; }
    else if (b <192) { W=wv;  Wt=wqkvT; K=128; lN=7; rel=b-128; roff=256; }
    else if (b <256) { W=wo;  Wt=woT;   K=128; lN=7; rel=b-192; }
    else if (b <512) { W=w1;  Wt=w1T;   K=128; lN=9; rel=b-256; }
    else if (b <768) { W=w2;  Wt=w2T;   K=512; lN=7; rel=b-512; }
    else             { W=wsa; Wt=wsaTt; K=128; lN=7; rel=b-768; }
    int i = rel*256 + t;
    int k = i >> lN, n = i & ((1<<lN)-1);
    Wt[(size_t)(n+roff)*K + k] = f2b(W[i]);
  } else if (b < 896){
    if (t >= 256) return;
    int i = (b-832)*256 + t;        // 0..16383
    int c = i>>7, d = i&127;
    float s = 0.f;
    #pragma unroll
    for (int h=0;h<HH;++h) s += w_sq[(size_t)c*(HH*DDIM) + h*DDIM + d];
    wbarT[d*DDIM + c] = f2b(0.25f*s);
  } else if (b < 898){
    if (t >= 256) return;
    int idx = (b-896)*256 + t;      // 0..511
    if (idx < 128){
      float s = 0.f;
      #pragma unroll
      for (int h=0;h<HH;++h) s += b_sq[h*DDIM + idx];
      bbar[idx] = 0.25f*s;
    } else if (idx < 512){
      int j = idx - 128;            // 0..383
      float v = (j<128) ? bq[j] : (j<256) ? bk[j-128] : bv[j-256];
      qkv_bias[j] = v;
    }
  } else if (b == 898){
    __shared__ int s_cnt[NN];
    s_cnt[t] = 0;
    __syncthreads();
    for (int e=t; e<E; e+=512) atomicAdd(&s_cnt[receivers[e]], 1);
    __syncthreads();
    int deg = s_cnt[t];
    int acc = 0, myrank = 0;
    for (int i=0;i<NN;++i){
      int di = s_cnt[i];                       // uniform i -> LDS broadcast
      acc    += (i<t) ? di : 0;
      myrank += ((di > deg) || (di == deg && i < t)) ? 1 : 0;
    }
    off[t] = acc;
    if (t==NN-1) off[NN] = acc + deg;
    perm[myrank] = t;
  } else {
    __shared__ int hc[NN];
    int c = b - 899;
    for (int i=t;i<NN;i+=512) hc[i]=0;
    __syncthreads();
    if (t < ECH){
      int e = c*ECH + t;
      if (e < E) atomicAdd(&hc[receivers[e]], 1);
    }
    __syncthreads();
    for (int i=t;i<NN;i+=512) chunk_cnt[(size_t)c*NN + i] = hc[i];
  }
}

// ---- slot scatter with on-the-fly base ----
__global__ __launch_bounds__(64) void slot_k(const int* __restrict__ senders,
    const int* __restrict__ receivers, const int* __restrict__ off,
    const int* __restrict__ chunk_cnt, int* __restrict__ slot_snd, int E){
  int t = threadIdx.x, c = blockIdx.x;
  int e = c*ECH + t;
  bool valid = (e < E);
  int r  = valid ? receivers[e] : -1;
  int sd = valid ? senders[e]   : 0;
  int base = 0;
  if (valid){
    base = off[r];
    for (int cp=0; cp<c; ++cp) base += chunk_cnt[(size_t)cp*NN + r];
  }
  int rank = 0;
  #pragma unroll
  for (int i=0;i<64;++i){
    int ri = __shfl(r, i);
    rank += (i < t && ri == r) ? 1 : 0;
  }
  if (valid) slot_snd[base + rank] = sd;
}

// ------- Fused LN1 + QKV GEMM: qkvb = LN1(nodes) @ wqkvT^T + b. -------
__global__ __launch_bounds__(256) void gemm_ln1qkv_k(const float* __restrict__ X,
    const float* __restrict__ lns, const float* __restrict__ lnb,
    const bf16* __restrict__ Wt, const float* __restrict__ bias,
    bf16* __restrict__ C){
  __shared__ bf16 sA[64][136];   // LN1(nodes) tile, full K
  __shared__ bf16 sB[64][72];
  int t = threadIdx.x, bm = blockIdx.x;
  int w = t>>6, lane = t&63, ls = lane&15, lg = lane>>4;
  int wr = w>>1, wc = w&1;
  {
    int r = t>>2, q = t&3;
    float vals[32];
    const float* xr = X + (size_t)(bm*64 + r)*DDIM + q*32;
    #pragma unroll
    for (int p=0;p<8;++p){
      float4 v = *(const float4*)(xr + p*4);
      vals[p*4+0]=v.x; vals[p*4+1]=v.y; vals[p*4+2]=v.z; vals[p*4+3]=v.w;
    }
    float s=0.f, sq=0.f;
    #pragma unroll
    for (int j=0;j<32;++j){ s += vals[j]; sq += vals[j]*vals[j]; }
    s  += __shfl_xor(s, 1);  s  += __shfl_xor(s, 2);
    sq += __shfl_xor(sq, 1); sq += __shfl_xor(sq, 2);
    float mu   = s*(1.0f/DDIM);
    float var  = sq*(1.0f/DDIM) - mu*mu;
    float rstd = rsqrtf(var + 1e-5f);
    #pragma unroll
    for (int p=0;p<4;++p){
      bf16 pv[8];
      #pragma unroll
      for (int j=0;j<8;++j){
        int cidx = q*32 + p*8 + j;
        pv[j] = f2b((vals[p*8+j]-mu)*rstd*lns[cidx] + lnb[cidx]);
      }
      *(int4*)(&sA[r][q*32 + p*8]) = *(const int4*)pv;
    }
  }
  for (int bn=0; bn<6; ++bn){
    f4v acc[2][2] = {};
    for (int ks=0; ks<128; ks+=64){
      __syncthreads();
      #pragma unroll
      for (int p=0;p<2;++p){
        int r = p*32 + (t>>3), cc = (t&7)*8;
        *(int4*)(&sB[r][cc]) = *(const int4*)(Wt + (size_t)(bn*64+r)*128 + ks + cc);
      }
      __syncthreads();
      #pragma unroll
      for (int k0=0;k0<64;k0+=32){
        int kc = ks + k0 + 8*lg;
        bf8v a0 = ldfrag(&sA[wr*32      + ls][kc]);
        bf8v a1 = ldfrag(&sA[wr*32 + 16 + ls][kc]);
        bf8v b0 = ldfrag(&sB[wc*32      + ls][k0 + 8*lg]);
        bf8v b1 = ldfrag(&sB[wc*32 + 16 + ls][k0 + 8*lg]);
        acc[0][0] = mfma16(a0, b0, acc[0][0]);
        acc[0][1] = mfma16(a0, b1, acc[0][1]);
        acc[1][0] = mfma16(a1, b0, acc[1][0]);
        acc[1][1] = mfma16(a1, b1, acc[1][1]);
      }
    }
    #pragma unroll
    for (int j=0;j<2;++j){
      int gcol = bn*64 + wc*32 + j*16 + ls;
      float bs = bias[gcol];
      #pragma unroll
      for (int i=0;i<2;++i)
        #pragma unroll
        for (int r=0;r<4;++r){
          int grow = bm*64 + wr*32 + i*16 + 4*lg + r;
          C[(size_t)grow*384 + gcol] = f2b(acc[i][j][r] + bs);
        }
    }
  }
}

// ------- w1 GEMM, A staged once: hb = gelu(xn2 @ w1T^T + b1), 8 bn chunks -------
__global__ __launch_bounds__(256) void gemm_w1_k(const bf16* __restrict__ A,
    const bf16* __restrict__ Wt, const float* __restrict__ bias,
    bf16* __restrict__ C){
  __shared__ bf16 sA[64][136];   // xn2 tile, full K
  __shared__ bf16 sB[64][72];
  int t = threadIdx.x, bm = blockIdx.x;
  int w = t>>6, lane = t&63, ls = lane&15, lg = lane>>4;
  int wr = w>>1, wc = w&1;
  #pragma unroll
  for (int p=0;p<4;++p){
    int idx = p*256 + t;
    int r = idx>>4, c8 = (idx&15)*8;
    *(int4*)(&sA[r][c8]) = *(const int4*)(A + (size_t)(bm*64+r)*128 + c8);
  }
  for (int bn=0; bn<8; ++bn){
    f4v acc[2][2] = {};
    for (int ks=0; ks<128; ks+=64){
      __syncthreads();   // sA ready (first iter); prior sB reads done
      #pragma unroll
      for (int p=0;p<2;++p){
        int r = p*32 + (t>>3), cc = (t&7)*8;
        *(int4*)(&sB[r][cc]) = *(const int4*)(Wt + (size_t)(bn*64+r)*128 + ks + cc);
      }
      __syncthreads();
      #pragma unroll
      for (int k0=0;k0<64;k0+=32){
        int kc = ks + k0 + 8*lg;
        bf8v a0 = ldfrag(&sA[wr*32      + ls][kc]);
        bf8v a1 = ldfrag(&sA[wr*32 + 16 + ls][kc]);
        bf8v b0 = ldfrag(&sB[wc*32      + ls][k0 + 8*lg]);
        bf8v b1 = ldfrag(&sB[wc*32 + 16 + ls][k0 + 8*lg]);
        acc[0][0] = mfma16(a0, b0, acc[0][0]);
        acc[0][1] = mfma16(a0, b1, acc[0][1]);
        acc[1][0] = mfma16(a1, b0, acc[1][0]);
        acc[1][1] = mfma16(a1, b1, acc[1][1]);
      }
    }
    #pragma unroll
    for (int j=0;j<2;++j){
      int gcol = bn*64 + wc*32 + j*16 + ls;
      float bs = bias[gcol];
      #pragma unroll
      for (int i=0;i<2;++i)
        #pragma unroll
        for (int r=0;r<4;++r){
          int grow = bm*64 + wr*32 + i*16 + 4*lg + r;
          C[(size_t)grow*512 + gcol] = f2b(gelu_f(acc[i][j][r] + bs));
        }
    }
  }
}

// ------- Fused attention + wo GEMM + residual + LN2: block = node (r19) -------
__global__ __launch_bounds__(256) void attn_wo_k(const bf16* __restrict__ qkvb,
    const bf16* __restrict__ woT, const float* __restrict__ bias,
    const float* __restrict__ Rres, const float* __restrict__ lns,
    const float* __restrict__ lnb, bf16* __restrict__ n2out,
    bf16* __restrict__ xnout){
  __shared__ bf16 sVT[128][72];
  __shared__ bf16 sP[4][64][72];
  __shared__ bf16 sB[128][72];
  __shared__ float s_st[2][2][32][2];
  bf16 (*sAtt)[136] = (bf16(*)[136])(&sP[0][0][0]);
  int t = threadIdx.x, n = blockIdx.x;
  int w = t>>6, lane = t&63, ls = lane&15, lg = lane>>4;
  const bf16* qbase = qkvb + (size_t)n*SSEQ*(3*DDIM);
  bf8v qf[4], kf[4];
  #pragma unroll
  for (int mi=0;mi<4;++mi)
    qf[mi] = ldfrag(qbase + (size_t)(16*mi + ls)*(3*DDIM) + 32*w + 8*lg);
  #pragma unroll
  for (int ni=0;ni<4;++ni)
    kf[ni] = ldfrag(qbase + (size_t)(16*ni + ls)*(3*DDIM) + DDIM + 32*w + 8*lg);
  for (int id = t; id < 1024; id += 256){
    int T = id>>4, c = id&15;
    int4 v = *(const int4*)(qbase + (size_t)T*(3*DDIM) + 2*DDIM + c*8);
    const bf16* pv = (const bf16*)&v;
    #pragma unroll
    for (int j=0;j<8;++j){
      int d = c*8 + j;
      sVT[d][T ^ (((d>>3)&7)<<3)] = pv[j];
    }
  }
  f4v accS[4][4];
  #pragma unroll
  for (int mi=0;mi<4;++mi)
    #pragma unroll
    for (int ni=0;ni<4;++ni){
      f4v z = {};
      accS[mi][ni] = mfma16(qf[mi], kf[ni], z);
    }
  __syncthreads();
  const float scale = 0.17677669529663687f;           // 1/sqrt(32)
  const float slope = 1.0f / (float)(4 << (2*w));     // 2^(-2(w+1))
  float den[4][4];
  #pragma unroll
  for (int mi=0;mi<4;++mi)
    #pragma unroll
    for (int r=0;r<4;++r) den[mi][r] = 0.f;
  #pragma unroll
  for (int mi=0;mi<4;++mi){
    #pragma unroll
    for (int ni=0;ni<4;++ni){
      #pragma unroll
      for (int r=0;r<4;++r){
        int rel = (16*ni + ls) - (16*mi + 4*lg + r);  // T - t
        float p = (rel <= 0) ? __expf(accS[mi][ni][r]*scale + slope*(float)rel) : 0.f;
        accS[mi][ni][r] = p;
        den[mi][r] += p;
      }
    }
  }
  #pragma unroll
  for (int mi=0;mi<4;++mi)
    #pragma unroll
    for (int r=0;r<4;++r){
      float d_ = den[mi][r];
      d_ += __shfl_xor(d_, 1);  d_ += __shfl_xor(d_, 2);
      d_ += __shfl_xor(d_, 4);  d_ += __shfl_xor(d_, 8);
      den[mi][r] = 1.0f / d_;
    }
  #pragma unroll
  for (int mi=0;mi<4;++mi)
    #pragma unroll
    for (int ni=0;ni<4;++ni)
      #pragma unroll
      for (int r=0;r<4;++r)
        sP[w][16*mi + 4*lg + r][16*ni + ls] = f2b(accS[mi][ni][r]*den[mi][r]);
  f4v oacc[4][2] = {};
  #pragma unroll
  for (int ks=0;ks<2;++ks){
    bf8v vf[2];
    #pragma unroll
    for (int ni2=0;ni2<2;++ni2){
      int d = 32*w + 16*ni2 + ls;
      vf[ni2] = ldfrag(&sVT[d][(32*ks + 8*lg) ^ (((d>>3)&7)<<3)]);
    }
    #pragma unroll
    for (int mi=0;mi<4;++mi){
      bf8v pa = ldfrag(&sP[w][16*mi + ls][32*ks + 8*lg]);
      #pragma unroll
      for (int ni2=0;ni2<2;++ni2)
        oacc[mi][ni2] = mfma16(pa, vf[ni2], oacc[mi][ni2]);
    }
  }
  __syncthreads();
  #pragma unroll
  for (int mi=0;mi<4;++mi)
    #pragma unroll
    for (int ni2=0;ni2<2;++ni2)
      #pragma unroll
      for (int r=0;r<4;++r)
        sAtt[16*mi + 4*lg + r][32*w + 16*ni2 + ls] = f2b(oacc[mi][ni2][r]);
  __syncthreads();
  int wr = w>>1, wc = w&1;
  f4v acc2[2][4] = {};
  for (int ks=0; ks<128; ks+=64){
    if (ks) __syncthreads();
    #pragma unroll
    for (int p=0;p<4;++p){
      int r = p*32 + (t>>3), cc = (t&7)*8;
      *(int4*)(&sB[r][cc]) = *(const int4*)(woT + (size_t)r*128 + ks + cc);
    }
    __syncthreads();
    #pragma unroll
    for (int k0=0;k0<64;k0+=32){
      int kc = ks + k0 + 8*lg;
      bf8v a0 = ldfrag(&sAtt[wr*32      + ls][kc]);
      bf8v a1 = ldfrag(&sAtt[wr*32 + 16 + ls][kc]);
      #pragma unroll
      for (int j=0;j<4;++j){
        bf8v bj = ldfrag(&sB[wc*64 + j*16 + ls][k0 + 8*lg]);
        acc2[0][j] = mfma16(a0, bj, acc2[0][j]);
        acc2[1][j] = mfma16(a1, bj, acc2[1][j]);
      }
    }
  }
  float x[2][4][4];
  float psum[2][4], psq[2][4];
  #pragma unroll
  for (int i=0;i<2;++i)
    #pragma unroll
    for (int r=0;r<4;++r){ psum[i][r]=0.f; psq[i][r]=0.f; }
  #pragma unroll
  for (int i=0;i<2;++i){
    #pragma unroll
    for (int j=0;j<4;++j){
      int col = wc*64 + j*16 + ls;
      float bs = bias[col];
      #pragma unroll
      for (int r=0;r<4;++r){
        int row = n*64 + wr*32 + i*16 + 4*lg + r;
        float v = acc2[i][j][r] + bs + Rres[(size_t)row*128 + col];
        x[i][j][r] = v;
        psum[i][r] += v;
        psq[i][r]  += v*v;
        n2out[(size_t)row*128 + col] = f2b(v);
      }
    }
  }
  #pragma unroll
  for (int i=0;i<2;++i)
    #pragma unroll
    for (int r=0;r<4;++r){
      float s_=psum[i][r], q_=psq[i][r];
      s_ += __shfl_xor(s_,1); s_ += __shfl_xor(s_,2);
      s_ += __shfl_xor(s_,4); s_ += __shfl_xor(s_,8);
      q_ += __shfl_xor(q_,1); q_ += __shfl_xor(q_,2);
      q_ += __shfl_xor(q_,4); q_ += __shfl_xor(q_,8);
      if (ls == 0){
        int rl = i*16 + 4*lg + r;
        s_st[wr][wc][rl][0] = s_;
        s_st[wr][wc][rl][1] = q_;
      }
    }
  __syncthreads();
  #pragma unroll
  for (int i=0;i<2;++i){
    #pragma unroll
    for (int r=0;r<4;++r){
      int rl = i*16 + 4*lg + r;
      float s_ = s_st[wr][0][rl][0] + s_st[wr][1][rl][0];
      float q_ = s_st[wr][0][rl][1] + s_st[wr][1][rl][1];
      float mu = s_*(1.0f/DDIM);
      float var = q_*(1.0f/DDIM) - mu*mu;
      float rstd = rsqrtf(var + 1e-5f);
      int row = n*64 + wr*32 + rl;
      #pragma unroll
      for (int j=0;j<4;++j){
        int col = wc*64 + j*16 + ls;
        xnout[(size_t)row*128 + col] = f2b((x[i][j][r]-mu)*rstd*lns[col] + lnb[col]);
      }
    }
  }
}

// ------- Fused tail: r2 = LN3(hb@w2T + b2 + n2); yexp = exp(r2 @ wsaT^T) -------
__global__ __launch_bounds__(256) void gemm_w2_tail_k(const bf16* __restrict__ A,
    const bf16* __restrict__ Wt, const float* __restrict__ bias,
    const bf16* __restrict__ Rres, const float* __restrict__ lns,
    const float* __restrict__ lnb, const bf16* __restrict__ wsaT,
    bf16* __restrict__ r2out, bf16* __restrict__ yexpout){
  __shared__ bf16 sA[64][72];
  __shared__ bf16 sB[128][72];
  __shared__ bf16 sY[64][136];
  __shared__ float s_st[2][2][32][2];
  int t = threadIdx.x, bm = blockIdx.x;
  int w = t>>6, lane = t&63, ls = lane&15, lg = lane>>4;
  int wr = w>>1, wc = w&1;
  f4v acc[2][4] = {};
  for (int ks=0; ks<512; ks+=64){
    #pragma unroll
    for (int p=0;p<2;++p){
      int r = p*32 + (t>>3), cc = (t&7)*8;
      *(int4*)(&sA[r][cc]) = *(const int4*)(A + (size_t)(bm*64+r)*512 + ks + cc);
    }
    #pragma unroll
    for (int p=0;p<4;++p){
      int r = p*32 + (t>>3), cc = (t&7)*8;
      *(int4*)(&sB[r][cc]) = *(const int4*)(Wt + (size_t)r*512 + ks + cc);
    }
    __syncthreads();
    #pragma unroll
    for (int k0=0;k0<64;k0+=32){
      int kc = k0 + 8*lg;
      bf8v a0 = ldfrag(&sA[wr*32      + ls][kc]);
      bf8v a1 = ldfrag(&sA[wr*32 + 16 + ls][kc]);
      #pragma unroll
      for (int j=0;j<4;++j){
        bf8v bj = ldfrag(&sB[wc*64 + j*16 + ls][kc]);
        acc[0][j] = mfma16(a0, bj, acc[0][j]);
        acc[1][j] = mfma16(a1, bj, acc[1][j]);
      }
    }
    __syncthreads();
  }
  float x[2][4][4];
  float psum[2][4], psq[2][4];
  #pragma unroll
  for (int i=0;i<2;++i)
    #pragma unroll
    for (int r=0;r<4;++r){ psum[i][r]=0.f; psq[i][r]=0.f; }
  #pragma unroll
  for (int i=0;i<2;++i){
    #pragma unroll
    for (int j=0;j<4;++j){
      int col = wc*64 + j*16 + ls;
      float bs = bias[col];
      #pragma unroll
      for (int r=0;r<4;++r){
        int row = bm*64 + wr*32 + i*16 + 4*lg + r;
        float v = acc[i][j][r] + bs + b2f(Rres[(size_t)row*128 + col]);
        x[i][j][r] = v;
        psum[i][r] += v;
        psq[i][r]  += v*v;
      }
    }
  }
  #pragma unroll
  for (int i=0;i<2;++i)
    #pragma unroll
    for (int r=0;r<4;++r){
      float s_=psum[i][r], q_=psq[i][r];
      s_ += __shfl_xor(s_,1); s_ += __shfl_xor(s_,2);
      s_ += __shfl_xor(s_,4); s_ += __shfl_xor(s_,8);
      q_ += __shfl_xor(q_,1); q_ += __shfl_xor(q_,2);
      q_ += __shfl_xor(q_,4); q_ += __shfl_xor(q_,8);
      if (ls == 0){
        int rl = i*16 + 4*lg + r;
        s_st[wr][wc][rl][0] = s_;
        s_st[wr][wc][rl][1] = q_;
      }
    }
  __syncthreads();
  #pragma unroll
  for (int i=0;i<2;++i){
    #pragma unroll
    for (int r=0;r<4;++r){
      int rl = i*16 + 4*lg + r;
      float s_ = s_st[wr][0][rl][0] + s_st[wr][1][rl][0];
      float q_ = s_st[wr][0][rl][1] + s_st[wr][1][rl][1];
      float mu = s_*(1.0f/DDIM);
      float var = q_*(1.0f/DDIM) - mu*mu;
      float rstd = rsqrtf(var + 1e-5f);
      int row = bm*64 + wr*32 + rl;
      #pragma unroll
      for (int j=0;j<4;++j){
        int col = wc*64 + j*16 + ls;
        bf16 yb = f2b((x[i][j][r]-mu)*rstd*lns[col] + lnb[col]);
        r2out[(size_t)row*128 + col] = yb;
        sY[wr*32 + rl][col] = yb;
      }
    }
  }
  __syncthreads();
  f4v acc2[2][4] = {};
  for (int ks2=0; ks2<128; ks2+=64){
    #pragma unroll
    for (int p=0;p<4;++p){
      int r = p*32 + (t>>3), cc = (t&7)*8;
      *(int4*)(&sB[r][cc]) = *(const int4*)(wsaT + (size_t)r*128 + ks2 + cc);
    }
    __syncthreads();
    #pragma unroll
    for (int k0=0;k0<64;k0+=32){
      int kc = k0 + 8*lg;
      bf8v a0 = ldfrag(&sY[wr*32      + ls][ks2 + kc]);
      bf8v a1 = ldfrag(&sY[wr*32 + 16 + ls][ks2 + kc]);
      #pragma unroll
      for (int j=0;j<4;++j){
        bf8v bj = ldfrag(&sB[wc*64 + j*16 + ls][kc]);
        acc2[0][j] = mfma16(a0, bj, acc2[0][j]);
        acc2[1][j] = mfma16(a1, bj, acc2[1][j]);
      }
    }
    __syncthreads();
  }
  #pragma unroll
  for (int i=0;i<2;++i){
    #pragma unroll
    for (int j=0;j<4;++j){
      int col = wc*64 + j*16 + ls;
      #pragma unroll
      for (int r=0;r<4;++r){
        int row = bm*64 + wr*32 + i*16 + 4*lg + r;
        yexpout[(size_t)row*128 + col] = f2b(__expf(acc2[i][j][r]));
      }
    }
  }
}

// ----------------- Fused message stage v6 (r17, unchanged) -----------------
__global__ __launch_bounds__(256) void msg4_k(const bf16* __restrict__ yexp,
    const bf16* __restrict__ nodes3, const int* __restrict__ off,
    const int* __restrict__ slot_snd, const int* __restrict__ perm,
    const bf16* __restrict__ wbarT, const float* __restrict__ bbar,
    float* __restrict__ out){
  __shared__ bf16 sP[2][16][136];          // normalized P tiles (8.7KB)
  __shared__ bf16 s_sent[4][3][16][36];    // per-wave 16x32 sent tiles (13.8KB)
  int t = threadIdx.x, sc = blockIdx.y;
  int n = perm[blockIdx.x];
  int w = t>>6, lane = t&63, ls = lane&15, lg = lane>>4;
  int off0 = off[n], deg = off[n+1]-off0;
  int dbase = w*32;
  if (deg == 0){
    #pragma unroll
    for (int ct=0;ct<2;++ct)
      #pragma unroll
      for (int r=0;r<4;++r)
        out[((size_t)n*SSEQ + sc*16 + 4*lg + r)*DDIM + dbase + ct*16 + ls] = 0.f;
    return;
  }
  bf8v B[2][4];
  #pragma unroll
  for (int ct=0;ct<2;++ct)
    #pragma unroll
    for (int kb=0;kb<4;++kb)
      B[ct][kb] = ldfrag(wbarT + (size_t)(dbase + ct*16 + ls)*DDIM + kb*32 + lg*8);
  float bb[2];
  #pragma unroll
  for (int ct=0;ct<2;++ct) bb[ct] = bbar[dbase + ct*16 + ls];
  int rp = t>>4, cp = (t&15)*8;
  size_t prow = ((size_t)(sc*16 + rp))*DDIM + cp;
  float den8[8];
  #pragma unroll
  for (int j=0;j<8;++j) den8[j] = 0.f;
  {
    int k = 0;
    for (; k+2<=deg; k+=2){
      int s0 = slot_snd[off0+k], s1 = slot_snd[off0+k+1];
      int4 v0 = *(const int4*)(yexp + (size_t)s0*SSEQ*DDIM + prow);
      int4 v1 = *(const int4*)(yexp + (size_t)s1*SSEQ*DDIM + prow);
      const bf16* a = (const bf16*)&v0;
      const bf16* b = (const bf16*)&v1;
      #pragma unroll
      for (int j=0;j<8;++j) den8[j] += b2f(a[j]) + b2f(b[j]);
    }
    if (k < deg){
      int s0 = slot_snd[off0+k];
      int4 v = *(const int4*)(yexp + (size_t)s0*SSEQ*DDIM + prow);
      const bf16* a = (const bf16*)&v;
      #pragma unroll
      for (int j=0;j<8;++j) den8[j] += b2f(a[j]);
    }
  }
  #pragma unroll
  for (int j=0;j<8;++j) den8[j] = 1.0f/den8[j];   // now inv
  int rs = lane>>2, cs = (lane&3)*8;
  int4 yv1;
  {
    int snd = slot_snd[off0];
    int4 v = *(const int4*)(yexp + (size_t)snd*SSEQ*DDIM + prow);
    const bf16* a = (const bf16*)&v;
    bf16 pv[8];
    #pragma unroll
    for (int j=0;j<8;++j) pv[j] = f2b(b2f(a[j]) * den8[j]);
    *(int4*)&sP[0][rp][cp] = *(const int4*)pv;
    *(int4*)&s_sent[w][0][rs][cs] =
      *(const int4*)(nodes3 + ((size_t)snd*SSEQ + sc*16 + rs)*DDIM + dbase + cs);
  }
  if (deg > 1){
    int snd = slot_snd[off0+1];
    yv1 = *(const int4*)(yexp + (size_t)snd*SSEQ*DDIM + prow);
    *(int4*)&s_sent[w][1][rs][cs] =
      *(const int4*)(nodes3 + ((size_t)snd*SSEQ + sc*16 + rs)*DDIM + dbase + cs);
  }
  __syncthreads();
  f4v oacc[2] = {};
  int4 yvN;
  for (int k=0;k<deg;++k){
    int buf = k&1;
    if (k+2 < deg){
      int snd2 = slot_snd[off0+k+2];
      yvN = *(const int4*)(yexp + (size_t)snd2*SSEQ*DDIM + prow);
      *(int4*)&s_sent[w][(k+2)%3][rs][cs] =
        *(const int4*)(nodes3 + ((size_t)snd2*SSEQ + sc*16 + rs)*DDIM + dbase + cs);
    }
    if (k+1 < deg){
      const bf16* a = (const bf16*)&yv1;
      bf16 pv[8];
      #pragma unroll
      for (int j=0;j<8;++j) pv[j] = f2b(b2f(a[j]) * den8[j]);
      *(int4*)&sP[buf^1][rp][cp] = *(const int4*)pv;
    }
    bf8v a4[4];
    #pragma unroll
    for (int kb=0;kb<4;++kb) a4[kb] = ldfrag(&sP[buf][ls][kb*32 + lg*8]);
    f4v g[2] = {};
    #pragma unroll
    for (int kb=0;kb<4;++kb)
      #pragma unroll
      for (int ct=0;ct<2;++ct)
        g[ct] = mfma16(a4[kb], B[ct][kb], g[ct]);
    #pragma unroll
    for (int ct=0;ct<2;++ct)
      #pragma unroll
      for (int r=0;r<4;++r){
        float sent = b2f(s_sent[w][k%3][4*lg + r][ct*16 + ls]);
        oacc[ct][r] += (g[ct][r] + bb[ct]) * sent;
      }
    __syncthreads();
    yv1 = yvN;
  }
  #pragma unroll
  for (int ct=0;ct<2;++ct)
    #pragma unroll
    for (int r=0;r<4;++r)
      out[((size_t)n*SSEQ + sc*16 + 4*lg + r)*DDIM + dbase + ct*16 + ls] = oacc[ct][r];
}

// ----------------- driver -----------------
extern "C" void kernel_launch(void* const* d_in, const int* in_sizes, int n_in,
                              void* d_out, int out_size, void* d_ws, size_t ws_size,
                              hipStream_t stream){
  const float* nodes = (const float*)d_in[0];
  const int*  senders   = (const int*)d_in[1];
  const int*  receivers = (const int*)d_in[2];
  const float* ln1_s=(const float*)d_in[4];  const float* ln1_b=(const float*)d_in[5];
  const float* wq=(const float*)d_in[6];     const float* bq=(const float*)d_in[7];
  const float* wk=(const float*)d_in[8];     const float* bk=(const float*)d_in[9];
  const float* wv=(const float*)d_in[10];    const float* bv_=(const float*)d_in[11];
  const float* wo=(const float*)d_in[12];    const float* bo=(const float*)d_in[13];
  const float* ln2_s=(const float*)d_in[14]; const float* ln2_b=(const float*)d_in[15];
  const float* w1=(const float*)d_in[16];    const float* b1=(const float*)d_in[17];
  const float* w2=(const float*)d_in[18];    const float* b2=(const float*)d_in[19];
  const float* ln3_s=(const float*)d_in[20]; const float* ln3_b=(const float*)d_in[21];
  const float* w_sa=(const float*)d_in[22];
  const float* w_sq=(const float*)d_in[24];  const float* b_sq=(const float*)d_in[25];
  int E = in_sizes[1];
  int nch = (E + ECH - 1)/ECH;

  const size_t MB = 1024*1024;
  char* ws = (char*)d_ws;
  bf16* qkvb    = (bf16*)(ws +  8*MB);  // [NROWS,384] 24MB, dead after attn_wo
  bf16* n2      = (bf16*)(ws + 32*MB);
  bf16* xn2     = (bf16*)(ws + 48*MB);
  bf16* hb      = (bf16*)(ws);          // [NROWS,512] spans 0..32MB (qkvb dead)
  bf16* r2     = (bf16*)(ws + 64*MB);   // nodes3
  bf16* yexp   = (bf16*)(ws + 72*MB);   // exp(nodes3 @ w_sa_top)
  char* tail = ws + 88*MB;
  bf16*  wbarT   = (bf16*)tail;                       tail += DDIM*DDIM*2;   // 32KB
  float* bbar    = (float*)tail;                      tail += DDIM*4 + 512;
  float* qkv_bias= (float*)tail;                      tail += 3*DDIM*4;
  int*   off     = (int*)tail;                        tail += (NN+8)*4;
  int*   slot_snd= (int*)tail;                        tail += EMAX*4;
  int*   perm    = (int*)tail;                        tail += NN*4;
  int*   ccnt    = (int*)tail;                        tail += 64*NN*4;       // 128KB
  bf16*  wqkvT   = (bf16*)tail;                       tail += 384*128*2;
  bf16*  woT     = (bf16*)tail;                       tail += 128*128*2;
  bf16*  w1T     = (bf16*)tail;                       tail += 128*512*2;
  bf16*  w2T     = (bf16*)tail;                       tail += 512*128*2;
  bf16*  wsaTt   = (bf16*)tail;                       tail += 128*128*2;

  // prep (weights) + CSR-off/perm + histograms; then slot (with on-the-fly base)
  prep_all_k<<<899+nch,512,0,stream>>>(wq,wk,wv,wo,w1,w2,w_sa,w_sq,b_sq,bq,bk,bv_,
                                       receivers,
                                       wqkvT,woT,w1T,w2T,wsaTt,wbarT,bbar,qkv_bias,
                                       off, perm, ccnt, E);
  slot_k<<<nch,64,0,stream>>>(senders, receivers, off, ccnt, slot_snd, E);

  // stage A: LN1+QKV -> fused attention+wo+LN2
  gemm_ln1qkv_k<<<NROWS/64,256,0,stream>>>(nodes, ln1_s, ln1_b, wqkvT, qkv_bias, qkvb);
  attn_wo_k<<<NN,256,0,stream>>>(qkvb, woT, bo, nodes, ln2_s, ln2_b, n2, xn2);
  // FFN (w1: A staged once, 8 internal column chunks)
  gemm_w1_k<<<NROWS/64,256,0,stream>>>(xn2, w1T, b1, hb);
  gemm_w2_tail_k<<<NROWS/64,256,0,stream>>>(hb, w2T, b2, n2, ln3_s, ln3_b, wsaTt, r2, yexp);

  // message stage
  msg4_k<<<dim3(NN,4),256,0,stream>>>(yexp, r2, off, slot_snd, perm, wbarT, bbar, (float*)d_out);
}

// Round 21
// 140.628 us; speedup vs baseline: 1.0563x; 1.0563x over previous
//
#include <hip/hip_runtime.h>
#include <hip/hip_bf16.h>

typedef __hip_bfloat16 bf16;
typedef __attribute__((ext_vector_type(8))) __bf16 bf8v;   // MFMA A/B frag (4 VGPR)
typedef __attribute__((ext_vector_type(4))) float  f4v;    // MFMA C/D frag

#define NN 512          // nodes
#define SSEQ 64         // seq len
#define DDIM 128        // model dim
#define HH 4            // heads
#define NROWS (NN*SSEQ) // 32768
#define EMAX 4096       // edge capacity (problem-fixed E)
#define ECH 64          // edges per rank-chunk

__device__ __forceinline__ float b2f(bf16 x){ return __bfloat162float(x); }
__device__ __forceinline__ bf16 f2b(float x){ return __float2bfloat16(x); }
__device__ __forceinline__ float ldf(float x){ return x; }
__device__ __forceinline__ float ldf(bf16 x){ return b2f(x); }

__device__ __forceinline__ f4v mfma16(bf8v a, bf8v b, f4v c){
  return __builtin_amdgcn_mfma_f32_16x16x32_bf16(a, b, c, 0, 0, 0);
}
__device__ __forceinline__ bf8v ldfrag(const void* p){
  return __builtin_bit_cast(bf8v, *(const int4*)p);
}
__device__ __forceinline__ float gelu_f(float v){
  return 0.5f*v*(1.0f + tanhf(0.7978845608028654f*(v + 0.044715f*v*v*v)));
}

// ---- merged prep + CSR offsets/perm + per-chunk histograms (all independent) ----
__global__ __launch_bounds__(512) void prep_all_k(
    const float* wq, const float* wk, const float* wv, const float* wo,
    const float* w1, const float* w2, const float* wsa,
    const float* w_sq, const float* b_sq,
    const float* bq, const float* bk, const float* bv,
    const int* __restrict__ receivers,
    bf16* wqkvT, bf16* woT, bf16* w1T, bf16* w2T, bf16* wsaTt,
    bf16* wbarT, float* bbar, float* qkv_bias,
    int* off, int* perm, int* chunk_cnt, int E){
  int b = blockIdx.x, t = threadIdx.x;
  if (b < 832){
    if (t >= 256) return;
    const float* W; bf16* Wt; int K, lN, rel, roff = 0;
    if      (b < 64) { W=wq;  Wt=wqkvT; K=128; lN=7; rel=b;     roff=0;   }
    else if (b <128) { W=wk;  Wt=wqkvT; K=128; lN=7; rel=b-64;  roff=128; }
    else if (b <192) { W=wv;  Wt=wqkvT; K=128; lN=7; rel=b-128; roff=256; }
    else if (b <256) { W=wo;  Wt=woT;   K=128; lN=7; rel=b-192; }
    else if (b <512) { W=w1;  Wt=w1T;   K=128; lN=9; rel=b-256; }
    else if (b <768) { W=w2;  Wt=w2T;   K=512; lN=7; rel=b-512; }
    else             { W=wsa; Wt=wsaTt; K=128; lN=7; rel=b-768; }
    int i = rel*256 + t;
    int k = i >> lN, n = i & ((1<<lN)-1);
    Wt[(size_t)(n+roff)*K + k] = f2b(W[i]);
  } else if (b < 896){
    if (t >= 256) return;
    int i = (b-832)*256 + t;        // 0..16383
    int c = i>>7, d = i&127;
    float s = 0.f;
    #pragma unroll
    for (int h=0;h<HH;++h) s += w_sq[(size_t)c*(HH*DDIM) + h*DDIM + d];
    wbarT[d*DDIM + c] = f2b(0.25f*s);
  } else if (b < 898){
    if (t >= 256) return;
    int idx = (b-896)*256 + t;      // 0..511
    if (idx < 128){
      float s = 0.f;
      #pragma unroll
      for (int h=0;h<HH;++h) s += b_sq[h*DDIM + idx];
      bbar[idx] = 0.25f*s;
    } else if (idx < 512){
      int j = idx - 128;            // 0..383
      float v = (j<128) ? bq[j] : (j<256) ? bk[j-128] : bv[j-256];
      qkv_bias[j] = v;
    }
  } else if (b == 898){
    __shared__ int s_cnt[NN];
    s_cnt[t] = 0;
    __syncthreads();
    for (int e=t; e<E; e+=512) atomicAdd(&s_cnt[receivers[e]], 1);
    __syncthreads();
    int deg = s_cnt[t];
    int acc = 0, myrank = 0;
    for (int i=0;i<NN;++i){
      int di = s_cnt[i];                       // uniform i -> LDS broadcast
      acc    += (i<t) ? di : 0;
      myrank += ((di > deg) || (di == deg && i < t)) ? 1 : 0;
    }
    off[t] = acc;
    if (t==NN-1) off[NN] = acc + deg;
    perm[myrank] = t;
  } else {
    __shared__ int hc[NN];
    int c = b - 899;
    for (int i=t;i<NN;i+=512) hc[i]=0;
    __syncthreads();
    if (t < ECH){
      int e = c*ECH + t;
      if (e < E) atomicAdd(&hc[receivers[e]], 1);
    }
    __syncthreads();
    for (int i=t;i<NN;i+=512) chunk_cnt[(size_t)c*NN + i] = hc[i];
  }
}

// ---- slot scatter with on-the-fly base: base(c,r) = off[r] + sum_{c'<c} ccnt[c'][r] ----
__global__ __launch_bounds__(64) void slot_k(const int* __restrict__ senders,
    const int* __restrict__ receivers, const int* __restrict__ off,
    const int* __restrict__ chunk_cnt, int* __restrict__ slot_snd, int E){
  int t = threadIdx.x, c = blockIdx.x;
  int e = c*ECH + t;
  bool valid = (e < E);
  int r  = valid ? receivers[e] : -1;
  int sd = valid ? senders[e]   : 0;
  int base = 0;
  if (valid){
    base = off[r];
    for (int cp=0; cp<c; ++cp) base += chunk_cnt[(size_t)cp*NN + r];
  }
  int rank = 0;
  #pragma unroll
  for (int i=0;i<64;++i){
    int ri = __shfl(r, i);
    rank += (i < t && ri == r) ? 1 : 0;
  }
  if (valid) slot_snd[base + rank] = sd;
}

// ------- Fused LN1 + QKV GEMM: qkvb = LN1(nodes) @ wqkvT^T + b. -------
__global__ __launch_bounds__(256) void gemm_ln1qkv_k(const float* __restrict__ X,
    const float* __restrict__ lns, const float* __restrict__ lnb,
    const bf16* __restrict__ Wt, const float* __restrict__ bias,
    bf16* __restrict__ C){
  __shared__ bf16 sA[64][136];   // LN1(nodes) tile, full K
  __shared__ bf16 sB[64][72];
  int t = threadIdx.x, bm = blockIdx.x;
  int w = t>>6, lane = t&63, ls = lane&15, lg = lane>>4;
  int wr = w>>1, wc = w&1;
  {
    int r = t>>2, q = t&3;
    float vals[32];
    const float* xr = X + (size_t)(bm*64 + r)*DDIM + q*32;
    #pragma unroll
    for (int p=0;p<8;++p){
      float4 v = *(const float4*)(xr + p*4);
      vals[p*4+0]=v.x; vals[p*4+1]=v.y; vals[p*4+2]=v.z; vals[p*4+3]=v.w;
    }
    float s=0.f, sq=0.f;
    #pragma unroll
    for (int j=0;j<32;++j){ s += vals[j]; sq += vals[j]*vals[j]; }
    s  += __shfl_xor(s, 1);  s  += __shfl_xor(s, 2);
    sq += __shfl_xor(sq, 1); sq += __shfl_xor(sq, 2);
    float mu   = s*(1.0f/DDIM);
    float var  = sq*(1.0f/DDIM) - mu*mu;
    float rstd = rsqrtf(var + 1e-5f);
    #pragma unroll
    for (int p=0;p<4;++p){
      bf16 pv[8];
      #pragma unroll
      for (int j=0;j<8;++j){
        int cidx = q*32 + p*8 + j;
        pv[j] = f2b((vals[p*8+j]-mu)*rstd*lns[cidx] + lnb[cidx]);
      }
      *(int4*)(&sA[r][q*32 + p*8]) = *(const int4*)pv;
    }
  }
  for (int bn=0; bn<6; ++bn){
    f4v acc[2][2] = {};
    for (int ks=0; ks<128; ks+=64){
      __syncthreads();
      #pragma unroll
      for (int p=0;p<2;++p){
        int r = p*32 + (t>>3), cc = (t&7)*8;
        *(int4*)(&sB[r][cc]) = *(const int4*)(Wt + (size_t)(bn*64+r)*128 + ks + cc);
      }
      __syncthreads();
      #pragma unroll
      for (int k0=0;k0<64;k0+=32){
        int kc = ks + k0 + 8*lg;
        bf8v a0 = ldfrag(&sA[wr*32      + ls][kc]);
        bf8v a1 = ldfrag(&sA[wr*32 + 16 + ls][kc]);
        bf8v b0 = ldfrag(&sB[wc*32      + ls][k0 + 8*lg]);
        bf8v b1 = ldfrag(&sB[wc*32 + 16 + ls][k0 + 8*lg]);
        acc[0][0] = mfma16(a0, b0, acc[0][0]);
        acc[0][1] = mfma16(a0, b1, acc[0][1]);
        acc[1][0] = mfma16(a1, b0, acc[1][0]);
        acc[1][1] = mfma16(a1, b1, acc[1][1]);
      }
    }
    #pragma unroll
    for (int j=0;j<2;++j){
      int gcol = bn*64 + wc*32 + j*16 + ls;
      float bs = bias[gcol];
      #pragma unroll
      for (int i=0;i<2;++i)
        #pragma unroll
        for (int r=0;r<4;++r){
          int grow = bm*64 + wr*32 + i*16 + 4*lg + r;
          C[(size_t)grow*384 + gcol] = f2b(acc[i][j][r] + bs);
        }
    }
  }
}

// ----------------- MFMA GEMM: C = act(A@Wt^T + b) (+R), BM=BN=64 -----------------
template<int KT, int ACT, typename TR, bool RES, bool BIAS>
__global__ __launch_bounds__(256) void gemm_m(const bf16* __restrict__ A,
    const bf16* __restrict__ Wt, const float* __restrict__ bias,
    const TR* __restrict__ R, bf16* __restrict__ C, int N){
  __shared__ bf16 sA[64][72];    // +8 pad
  __shared__ bf16 sB[64][72];
  int t = threadIdx.x;
  int bm = blockIdx.x, bn = blockIdx.y;
  int w = t>>6, lane = t&63;
  int wr = w>>1, wc = w&1;
  f4v acc[2][2] = {};
  for (int ks=0; ks<KT; ks+=64){
    #pragma unroll
    for (int p=0;p<2;++p){
      int r = p*32 + (t>>3), cc = (t&7)*8;
      *(int4*)(&sA[r][cc]) = *(const int4*)(A  + (size_t)(bm*64+r)*KT + ks + cc);
      *(int4*)(&sB[r][cc]) = *(const int4*)(Wt + (size_t)(bn*64+r)*KT + ks + cc);
    }
    __syncthreads();
    #pragma unroll
    for (int k0=0;k0<64;k0+=32){
      int kc = k0 + 8*(lane>>4);
      bf8v a0 = ldfrag(&sA[wr*32      + (lane&15)][kc]);
      bf8v a1 = ldfrag(&sA[wr*32 + 16 + (lane&15)][kc]);
      bf8v b0 = ldfrag(&sB[wc*32      + (lane&15)][kc]);
      bf8v b1 = ldfrag(&sB[wc*32 + 16 + (lane&15)][kc]);
      acc[0][0] = mfma16(a0, b0, acc[0][0]);
      acc[0][1] = mfma16(a0, b1, acc[0][1]);
      acc[1][0] = mfma16(a1, b0, acc[1][0]);
      acc[1][1] = mfma16(a1, b1, acc[1][1]);
    }
    __syncthreads();
  }
  #pragma unroll
  for (int j=0;j<2;++j){
    int gcol = bn*64 + wc*32 + j*16 + (lane&15);
    float bs = BIAS ? bias[gcol] : 0.f;
    #pragma unroll
    for (int i=0;i<2;++i){
      #pragma unroll
      for (int r=0;r<4;++r){
        int grow = bm*64 + wr*32 + i*16 + 4*(lane>>4) + r;
        float v = acc[i][j][r] + bs;
        if (ACT==1) v = gelu_f(v);
        if (ACT==2) v = __expf(v);
        if (RES) v += ldf(R[(size_t)grow*N + gcol]);
        C[(size_t)grow*N + gcol] = f2b(v);
      }
    }
  }
}

// ------- Fused attention + wo GEMM + residual + LN2: block = node -------
__global__ __launch_bounds__(256) void attn_wo_k(const bf16* __restrict__ qkvb,
    const bf16* __restrict__ woT, const float* __restrict__ bias,
    const float* __restrict__ Rres, const float* __restrict__ lns,
    const float* __restrict__ lnb, bf16* __restrict__ n2out,
    bf16* __restrict__ xnout){
  __shared__ bf16 sVT[128][72];
  __shared__ bf16 sP[4][64][72];
  __shared__ bf16 sB[128][72];
  __shared__ float s_st[2][2][32][2];
  bf16 (*sAtt)[136] = (bf16(*)[136])(&sP[0][0][0]);
  int t = threadIdx.x, n = blockIdx.x;
  int w = t>>6, lane = t&63, ls = lane&15, lg = lane>>4;
  const bf16* qbase = qkvb + (size_t)n*SSEQ*(3*DDIM);
  bf8v qf[4], kf[4];
  #pragma unroll
  for (int mi=0;mi<4;++mi)
    qf[mi] = ldfrag(qbase + (size_t)(16*mi + ls)*(3*DDIM) + 32*w + 8*lg);
  #pragma unroll
  for (int ni=0;ni<4;++ni)
    kf[ni] = ldfrag(qbase + (size_t)(16*ni + ls)*(3*DDIM) + DDIM + 32*w + 8*lg);
  for (int id = t; id < 1024; id += 256){
    int T = id>>4, c = id&15;
    int4 v = *(const int4*)(qbase + (size_t)T*(3*DDIM) + 2*DDIM + c*8);
    const bf16* pv = (const bf16*)&v;
    #pragma unroll
    for (int j=0;j<8;++j){
      int d = c*8 + j;
      sVT[d][T ^ (((d>>3)&7)<<3)] = pv[j];
    }
  }
  f4v accS[4][4];
  #pragma unroll
  for (int mi=0;mi<4;++mi)
    #pragma unroll
    for (int ni=0;ni<4;++ni){
      f4v z = {};
      accS[mi][ni] = mfma16(qf[mi], kf[ni], z);
    }
  __syncthreads();
  const float scale = 0.17677669529663687f;           // 1/sqrt(32)
  const float slope = 1.0f / (float)(4 << (2*w));     // 2^(-2(w+1))
  float den[4][4];
  #pragma unroll
  for (int mi=0;mi<4;++mi)
    #pragma unroll
    for (int r=0;r<4;++r) den[mi][r] = 0.f;
  #pragma unroll
  for (int mi=0;mi<4;++mi){
    #pragma unroll
    for (int ni=0;ni<4;++ni){
      #pragma unroll
      for (int r=0;r<4;++r){
        int rel = (16*ni + ls) - (16*mi + 4*lg + r);  // T - t
        float p = (rel <= 0) ? __expf(accS[mi][ni][r]*scale + slope*(float)rel) : 0.f;
        accS[mi][ni][r] = p;
        den[mi][r] += p;
      }
    }
  }
  #pragma unroll
  for (int mi=0;mi<4;++mi)
    #pragma unroll
    for (int r=0;r<4;++r){
      float d_ = den[mi][r];
      d_ += __shfl_xor(d_, 1);  d_ += __shfl_xor(d_, 2);
      d_ += __shfl_xor(d_, 4);  d_ += __shfl_xor(d_, 8);
      den[mi][r] = 1.0f / d_;
    }
  #pragma unroll
  for (int mi=0;mi<4;++mi)
    #pragma unroll
    for (int ni=0;ni<4;++ni)
      #pragma unroll
      for (int r=0;r<4;++r)
        sP[w][16*mi + 4*lg + r][16*ni + ls] = f2b(accS[mi][ni][r]*den[mi][r]);
  f4v oacc[4][2] = {};
  #pragma unroll
  for (int ks=0;ks<2;++ks){
    bf8v vf[2];
    #pragma unroll
    for (int ni2=0;ni2<2;++ni2){
      int d = 32*w + 16*ni2 + ls;
      vf[ni2] = ldfrag(&sVT[d][(32*ks + 8*lg) ^ (((d>>3)&7)<<3)]);
    }
    #pragma unroll
    for (int mi=0;mi<4;++mi){
      bf8v pa = ldfrag(&sP[w][16*mi + ls][32*ks + 8*lg]);
      #pragma unroll
      for (int ni2=0;ni2<2;++ni2)
        oacc[mi][ni2] = mfma16(pa, vf[ni2], oacc[mi][ni2]);
    }
  }
  __syncthreads();                      // all PV reads of sP complete
  #pragma unroll
  for (int mi=0;mi<4;++mi)
    #pragma unroll
    for (int ni2=0;ni2<2;++ni2)
      #pragma unroll
      for (int r=0;r<4;++r)
        sAtt[16*mi + 4*lg + r][32*w + 16*ni2 + ls] = f2b(oacc[mi][ni2][r]);
  __syncthreads();                      // sAtt complete
  int wr = w>>1, wc = w&1;
  f4v acc2[2][4] = {};
  for (int ks=0; ks<128; ks+=64){
    if (ks) __syncthreads();            // prior sB reads done
    #pragma unroll
    for (int p=0;p<4;++p){
      int r = p*32 + (t>>3), cc = (t&7)*8;
      *(int4*)(&sB[r][cc]) = *(const int4*)(woT + (size_t)r*128 + ks + cc);
    }
    __syncthreads();
    #pragma unroll
    for (int k0=0;k0<64;k0+=32){
      int kc = ks + k0 + 8*lg;
      bf8v a0 = ldfrag(&sAtt[wr*32      + ls][kc]);
      bf8v a1 = ldfrag(&sAtt[wr*32 + 16 + ls][kc]);
      #pragma unroll
      for (int j=0;j<4;++j){
        bf8v bj = ldfrag(&sB[wc*64 + j*16 + ls][k0 + 8*lg]);
        acc2[0][j] = mfma16(a0, bj, acc2[0][j]);
        acc2[1][j] = mfma16(a1, bj, acc2[1][j]);
      }
    }
  }
  float x[2][4][4];
  float psum[2][4], psq[2][4];
  #pragma unroll
  for (int i=0;i<2;++i)
    #pragma unroll
    for (int r=0;r<4;++r){ psum[i][r]=0.f; psq[i][r]=0.f; }
  #pragma unroll
  for (int i=0;i<2;++i){
    #pragma unroll
    for (int j=0;j<4;++j){
      int col = wc*64 + j*16 + ls;
      float bs = bias[col];
      #pragma unroll
      for (int r=0;r<4;++r){
        int row = n*64 + wr*32 + i*16 + 4*lg + r;
        float v = acc2[i][j][r] + bs + Rres[(size_t)row*128 + col];
        x[i][j][r] = v;
        psum[i][r] += v;
        psq[i][r]  += v*v;
        n2out[(size_t)row*128 + col] = f2b(v);
      }
    }
  }
  #pragma unroll
  for (int i=0;i<2;++i)
    #pragma unroll
    for (int r=0;r<4;++r){
      float s_=psum[i][r], q_=psq[i][r];
      s_ += __shfl_xor(s_,1); s_ += __shfl_xor(s_,2);
      s_ += __shfl_xor(s_,4); s_ += __shfl_xor(s_,8);
      q_ += __shfl_xor(q_,1); q_ += __shfl_xor(q_,2);
      q_ += __shfl_xor(q_,4); q_ += __shfl_xor(q_,8);
      if (ls == 0){
        int rl = i*16 + 4*lg + r;
        s_st[wr][wc][rl][0] = s_;
        s_st[wr][wc][rl][1] = q_;
      }
    }
  __syncthreads();
  #pragma unroll
  for (int i=0;i<2;++i){
    #pragma unroll
    for (int r=0;r<4;++r){
      int rl = i*16 + 4*lg + r;
      float s_ = s_st[wr][0][rl][0] + s_st[wr][1][rl][0];
      float q_ = s_st[wr][0][rl][1] + s_st[wr][1][rl][1];
      float mu = s_*(1.0f/DDIM);
      float var = q_*(1.0f/DDIM) - mu*mu;
      float rstd = rsqrtf(var + 1e-5f);
      int row = n*64 + wr*32 + rl;
      #pragma unroll
      for (int j=0;j<4;++j){
        int col = wc*64 + j*16 + ls;
        xnout[(size_t)row*128 + col] = f2b((x[i][j][r]-mu)*rstd*lns[col] + lnb[col]);
      }
    }
  }
}

// ------- Fused tail: r2 = LN3(hb@w2T + b2 + n2); yexp = exp(r2 @ wsaT^T) -------
__global__ __launch_bounds__(256) void gemm_w2_tail_k(const bf16* __restrict__ A,
    const bf16* __restrict__ Wt, const float* __restrict__ bias,
    const bf16* __restrict__ Rres, const float* __restrict__ lns,
    const float* __restrict__ lnb, const bf16* __restrict__ wsaT,
    bf16* __restrict__ r2out, bf16* __restrict__ yexpout){
  __shared__ bf16 sA[64][72];
  __shared__ bf16 sB[128][72];
  __shared__ bf16 sY[64][136];
  __shared__ float s_st[2][2][32][2];
  int t = threadIdx.x, bm = blockIdx.x;
  int w = t>>6, lane = t&63, ls = lane&15, lg = lane>>4;
  int wr = w>>1, wc = w&1;
  f4v acc[2][4] = {};
  for (int ks=0; ks<512; ks+=64){
    #pragma unroll
    for (int p=0;p<2;++p){
      int r = p*32 + (t>>3), cc = (t&7)*8;
      *(int4*)(&sA[r][cc]) = *(const int4*)(A + (size_t)(bm*64+r)*512 + ks + cc);
    }
    #pragma unroll
    for (int p=0;p<4;++p){
      int r = p*32 + (t>>3), cc = (t&7)*8;
      *(int4*)(&sB[r][cc]) = *(const int4*)(Wt + (size_t)r*512 + ks + cc);
    }
    __syncthreads();
    #pragma unroll
    for (int k0=0;k0<64;k0+=32){
      int kc = k0 + 8*lg;
      bf8v a0 = ldfrag(&sA[wr*32      + ls][kc]);
      bf8v a1 = ldfrag(&sA[wr*32 + 16 + ls][kc]);
      #pragma unroll
      for (int j=0;j<4;++j){
        bf8v bj = ldfrag(&sB[wc*64 + j*16 + ls][kc]);
        acc[0][j] = mfma16(a0, bj, acc[0][j]);
        acc[1][j] = mfma16(a1, bj, acc[1][j]);
      }
    }
    __syncthreads();
  }
  float x[2][4][4];
  float psum[2][4], psq[2][4];
  #pragma unroll
  for (int i=0;i<2;++i)
    #pragma unroll
    for (int r=0;r<4;++r){ psum[i][r]=0.f; psq[i][r]=0.f; }
  #pragma unroll
  for (int i=0;i<2;++i){
    #pragma unroll
    for (int j=0;j<4;++j){
      int col = wc*64 + j*16 + ls;
      float bs = bias[col];
      #pragma unroll
      for (int r=0;r<4;++r){
        int row = bm*64 + wr*32 + i*16 + 4*lg + r;
        float v = acc[i][j][r] + bs + b2f(Rres[(size_t)row*128 + col]);
        x[i][j][r] = v;
        psum[i][r] += v;
        psq[i][r]  += v*v;
      }
    }
  }
  #pragma unroll
  for (int i=0;i<2;++i)
    #pragma unroll
    for (int r=0;r<4;++r){
      float s_=psum[i][r], q_=psq[i][r];
      s_ += __shfl_xor(s_,1); s_ += __shfl_xor(s_,2);
      s_ += __shfl_xor(s_,4); s_ += __shfl_xor(s_,8);
      q_ += __shfl_xor(q_,1); q_ += __shfl_xor(q_,2);
      q_ += __shfl_xor(q_,4); q_ += __shfl_xor(q_,8);
      if (ls == 0){
        int rl = i*16 + 4*lg + r;
        s_st[wr][wc][rl][0] = s_;
        s_st[wr][wc][rl][1] = q_;
      }
    }
  __syncthreads();
  #pragma unroll
  for (int i=0;i<2;++i){
    #pragma unroll
    for (int r=0;r<4;++r){
      int rl = i*16 + 4*lg + r;
      float s_ = s_st[wr][0][rl][0] + s_st[wr][1][rl][0];
      float q_ = s_st[wr][0][rl][1] + s_st[wr][1][rl][1];
      float mu = s_*(1.0f/DDIM);
      float var = q_*(1.0f/DDIM) - mu*mu;
      float rstd = rsqrtf(var + 1e-5f);
      int row = bm*64 + wr*32 + rl;
      #pragma unroll
      for (int j=0;j<4;++j){
        int col = wc*64 + j*16 + ls;
        bf16 yb = f2b((x[i][j][r]-mu)*rstd*lns[col] + lnb[col]);
        r2out[(size_t)row*128 + col] = yb;
        sY[wr*32 + rl][col] = yb;
      }
    }
  }
  __syncthreads();
  f4v acc2[2][4] = {};
  for (int ks2=0; ks2<128; ks2+=64){
    #pragma unroll
    for (int p=0;p<4;++p){
      int r = p*32 + (t>>3), cc = (t&7)*8;
      *(int4*)(&sB[r][cc]) = *(const int4*)(wsaT + (size_t)r*128 + ks2 + cc);
    }
    __syncthreads();
    #pragma unroll
    for (int k0=0;k0<64;k0+=32){
      int kc = k0 + 8*lg;
      bf8v a0 = ldfrag(&sY[wr*32      + ls][ks2 + kc]);
      bf8v a1 = ldfrag(&sY[wr*32 + 16 + ls][ks2 + kc]);
      #pragma unroll
      for (int j=0;j<4;++j){
        bf8v bj = ldfrag(&sB[wc*64 + j*16 + ls][kc]);
        acc2[0][j] = mfma16(a0, bj, acc2[0][j]);
        acc2[1][j] = mfma16(a1, bj, acc2[1][j]);
      }
    }
    __syncthreads();
  }
  #pragma unroll
  for (int i=0;i<2;++i){
    #pragma unroll
    for (int j=0;j<4;++j){
      int col = wc*64 + j*16 + ls;
      #pragma unroll
      for (int r=0;r<4;++r){
        int row = bm*64 + wr*32 + i*16 + 4*lg + r;
        yexpout[(size_t)row*128 + col] = f2b(__expf(acc2[i][j][r]));
      }
    }
  }
}

// ----------------- Fused message stage v6 (r17, unchanged) -----------------
__global__ __launch_bounds__(256) void msg4_k(const bf16* __restrict__ yexp,
    const bf16* __restrict__ nodes3, const int* __restrict__ off,
    const int* __restrict__ slot_snd, const int* __restrict__ perm,
    const bf16* __restrict__ wbarT, const float* __restrict__ bbar,
    float* __restrict__ out){
  __shared__ bf16 sP[2][16][136];          // normalized P tiles (8.7KB)
  __shared__ bf16 s_sent[4][3][16][36];    // per-wave 16x32 sent tiles (13.8KB)
  int t = threadIdx.x, sc = blockIdx.y;
  int n = perm[blockIdx.x];
  int w = t>>6, lane = t&63, ls = lane&15, lg = lane>>4;
  int off0 = off[n], deg = off[n+1]-off0;
  int dbase = w*32;
  if (deg == 0){
    #pragma unroll
    for (int ct=0;ct<2;++ct)
      #pragma unroll
      for (int r=0;r<4;++r)
        out[((size_t)n*SSEQ + sc*16 + 4*lg + r)*DDIM + dbase + ct*16 + ls] = 0.f;
    return;
  }
  bf8v B[2][4];
  #pragma unroll
  for (int ct=0;ct<2;++ct)
    #pragma unroll
    for (int kb=0;kb<4;++kb)
      B[ct][kb] = ldfrag(wbarT + (size_t)(dbase + ct*16 + ls)*DDIM + kb*32 + lg*8);
  float bb[2];
  #pragma unroll
  for (int ct=0;ct<2;++ct) bb[ct] = bbar[dbase + ct*16 + ls];
  int rp = t>>4, cp = (t&15)*8;
  size_t prow = ((size_t)(sc*16 + rp))*DDIM + cp;
  float den8[8];
  #pragma unroll
  for (int j=0;j<8;++j) den8[j] = 0.f;
  {
    int k = 0;
    for (; k+2<=deg; k+=2){
      int s0 = slot_snd[off0+k], s1 = slot_snd[off0+k+1];
      int4 v0 = *(const int4*)(yexp + (size_t)s0*SSEQ*DDIM + prow);
      int4 v1 = *(const int4*)(yexp + (size_t)s1*SSEQ*DDIM + prow);
      const bf16* a = (const bf16*)&v0;
      const bf16* b = (const bf16*)&v1;
      #pragma unroll
      for (int j=0;j<8;++j) den8[j] += b2f(a[j]) + b2f(b[j]);
    }
    if (k < deg){
      int s0 = slot_snd[off0+k];
      int4 v = *(const int4*)(yexp + (size_t)s0*SSEQ*DDIM + prow);
      const bf16* a = (const bf16*)&v;
      #pragma unroll
      for (int j=0;j<8;++j) den8[j] += b2f(a[j]);
    }
  }
  #pragma unroll
  for (int j=0;j<8;++j) den8[j] = 1.0f/den8[j];   // now inv
  int rs = lane>>2, cs = (lane&3)*8;
  int4 yv1;
  {
    int snd = slot_snd[off0];
    int4 v = *(const int4*)(yexp + (size_t)snd*SSEQ*DDIM + prow);
    const bf16* a = (const bf16*)&v;
    bf16 pv[8];
    #pragma unroll
    for (int j=0;j<8;++j) pv[j] = f2b(b2f(a[j]) * den8[j]);
    *(int4*)&sP[0][rp][cp] = *(const int4*)pv;
    *(int4*)&s_sent[w][0][rs][cs] =
      *(const int4*)(nodes3 + ((size_t)snd*SSEQ + sc*16 + rs)*DDIM + dbase + cs);
  }
  if (deg > 1){
    int snd = slot_snd[off0+1];
    yv1 = *(const int4*)(yexp + (size_t)snd*SSEQ*DDIM + prow);
    *(int4*)&s_sent[w][1][rs][cs] =
      *(const int4*)(nodes3 + ((size_t)snd*SSEQ + sc*16 + rs)*DDIM + dbase + cs);
  }
  __syncthreads();
  f4v oacc[2] = {};
  int4 yvN;
  for (int k=0;k<deg;++k){
    int buf = k&1;
    if (k+2 < deg){
      int snd2 = slot_snd[off0+k+2];
      yvN = *(const int4*)(yexp + (size_t)snd2*SSEQ*DDIM + prow);
      *(int4*)&s_sent[w][(k+2)%3][rs][cs] =
        *(const int4*)(nodes3 + ((size_t)snd2*SSEQ + sc*16 + rs)*DDIM + dbase + cs);
    }
    if (k+1 < deg){
      const bf16* a = (const bf16*)&yv1;
      bf16 pv[8];
      #pragma unroll
      for (int j=0;j<8;++j) pv[j] = f2b(b2f(a[j]) * den8[j]);
      *(int4*)&sP[buf^1][rp][cp] = *(const int4*)pv;
    }
    bf8v a4[4];
    #pragma unroll
    for (int kb=0;kb<4;++kb) a4[kb] = ldfrag(&sP[buf][ls][kb*32 + lg*8]);
    f4v g[2] = {};
    #pragma unroll
    for (int kb=0;kb<4;++kb)
      #pragma unroll
      for (int ct=0;ct<2;++ct)
        g[ct] = mfma16(a4[kb], B[ct][kb], g[ct]);
    #pragma unroll
    for (int ct=0;ct<2;++ct)
      #pragma unroll
      for (int r=0;r<4;++r){
        float sent = b2f(s_sent[w][k%3][4*lg + r][ct*16 + ls]);
        oacc[ct][r] += (g[ct][r] + bb[ct]) * sent;
      }
    __syncthreads();
    yv1 = yvN;
  }
  #pragma unroll
  for (int ct=0;ct<2;++ct)
    #pragma unroll
    for (int r=0;r<4;++r)
      out[((size_t)n*SSEQ + sc*16 + 4*lg + r)*DDIM + dbase + ct*16 + ls] = oacc[ct][r];
}

// ----------------- driver -----------------
extern "C" void kernel_launch(void* const* d_in, const int* in_sizes, int n_in,
                              void* d_out, int out_size, void* d_ws, size_t ws_size,
                              hipStream_t stream){
  const float* nodes = (const float*)d_in[0];
  const int*  senders   = (const int*)d_in[1];
  const int*  receivers = (const int*)d_in[2];
  const float* ln1_s=(const float*)d_in[4];  const float* ln1_b=(const float*)d_in[5];
  const float* wq=(const float*)d_in[6];     const float* bq=(const float*)d_in[7];
  const float* wk=(const float*)d_in[8];     const float* bk=(const float*)d_in[9];
  const float* wv=(const float*)d_in[10];    const float* bv_=(const float*)d_in[11];
  const float* wo=(const float*)d_in[12];    const float* bo=(const float*)d_in[13];
  const float* ln2_s=(const float*)d_in[14]; const float* ln2_b=(const float*)d_in[15];
  const float* w1=(const float*)d_in[16];    const float* b1=(const float*)d_in[17];
  const float* w2=(const float*)d_in[18];    const float* b2=(const float*)d_in[19];
  const float* ln3_s=(const float*)d_in[20]; const float* ln3_b=(const float*)d_in[21];
  const float* w_sa=(const float*)d_in[22];
  const float* w_sq=(const float*)d_in[24];  const float* b_sq=(const float*)d_in[25];
  int E = in_sizes[1];
  int nch = (E + ECH - 1)/ECH;

  const size_t MB = 1024*1024;
  char* ws = (char*)d_ws;
  bf16* qkvb    = (bf16*)(ws +  8*MB);  // [NROWS,384] 24MB, dead after attn_wo
  bf16* n2      = (bf16*)(ws + 32*MB);
  bf16* xn2     = (bf16*)(ws + 48*MB);
  bf16* hb      = (bf16*)(ws);          // [NROWS,512] spans 0..32MB (qkvb dead)
  bf16* r2     = (bf16*)(ws + 64*MB);   // nodes3
  bf16* yexp   = (bf16*)(ws + 72*MB);   // exp(nodes3 @ w_sa_top)
  char* tail = ws + 88*MB;
  bf16*  wbarT   = (bf16*)tail;                       tail += DDIM*DDIM*2;   // 32KB
  float* bbar    = (float*)tail;                      tail += DDIM*4 + 512;
  float* qkv_bias= (float*)tail;                      tail += 3*DDIM*4;
  int*   off     = (int*)tail;                        tail += (NN+8)*4;
  int*   slot_snd= (int*)tail;                        tail += EMAX*4;
  int*   perm    = (int*)tail;                        tail += NN*4;
  int*   ccnt    = (int*)tail;                        tail += 64*NN*4;       // 128KB
  bf16*  wqkvT   = (bf16*)tail;                       tail += 384*128*2;
  bf16*  woT     = (bf16*)tail;                       tail += 128*128*2;
  bf16*  w1T     = (bf16*)tail;                       tail += 128*512*2;
  bf16*  w2T     = (bf16*)tail;                       tail += 512*128*2;
  bf16*  wsaTt   = (bf16*)tail;                       tail += 128*128*2;

  // prep (weights) + CSR-off/perm + histograms; then slot (with on-the-fly base)
  prep_all_k<<<899+nch,512,0,stream>>>(wq,wk,wv,wo,w1,w2,w_sa,w_sq,b_sq,bq,bk,bv_,
                                       receivers,
                                       wqkvT,woT,w1T,w2T,wsaTt,wbarT,bbar,qkv_bias,
                                       off, perm, ccnt, E);
  slot_k<<<nch,64,0,stream>>>(senders, receivers, off, ccnt, slot_snd, E);

  // stage A: LN1+QKV -> fused attention+wo+LN2
  gemm_ln1qkv_k<<<NROWS/64,256,0,stream>>>(nodes, ln1_s, ln1_b, wqkvT, qkv_bias, qkvb);
  attn_wo_k<<<NN,256,0,stream>>>(qkvb, woT, bo, nodes, ln2_s, ln2_b, n2, xn2);
  // FFN
  gemm_m<128,1,bf16,false,true><<<dim3(NROWS/64,8),256,0,stream>>>(xn2, w1T, b1, (const bf16*)nullptr, hb, 512);
  gemm_w2_tail_k<<<NROWS/64,256,0,stream>>>(hb, w2T, b2, n2, ln3_s, ln3_b, wsaTt, r2, yexp);

  // message stage
  msg4_k<<<dim3(NN,4),256,0,stream>>>(yexp, r2, off, slot_snd, perm, wbarT, bbar, (float*)d_out);
}